// Round 13
// baseline (231.264 us; speedup 1.0000x reference)
//
#include <hip/hip_runtime.h>
#include <hip/hip_bf16.h>

// Workspace byte offsets
#define OFF_G    0u        // bf16 [128][128]  GA[oc][ic] = sum_o wq[o,ic]*wk[o,oc]
#define OFF_WVT  32768u    // bf16 [128][128]  WA[oc][j] = wv[oc][j] * bns[oc]  (BN-folded)
#define OFF_RT   65536u    // f32  [128][12]   Rm[c][i]
#define OFF_BNS  71680u    // f32  [128]       (unused by attn now)
#define OFF_BNB  72192u    // f32  [128]       bias2 = bv*bns + beta - mean*bns
#define OFF_FLAG 72704u    // int: 1 if MFMA fragment-layout probe verified
#define OFF_W1   72768u    // bf16 [208][1280] fc1 weights, original k = c*10+m order
#define OFF_P    605248u   // bf16 [32768][1280] pooled, original k = c*10+m order

typedef __attribute__((ext_vector_type(8))) unsigned short ushort8_t;
typedef __attribute__((ext_vector_type(8))) __bf16 bf16x8;
typedef __attribute__((ext_vector_type(4))) float f32x4;

static __device__ __forceinline__ float bfbits2f(unsigned short u) {
    return __uint_as_float(((unsigned)u) << 16);
}
static __device__ __forceinline__ unsigned short f2bfbits(float f) {
    __hip_bfloat16 h = __float2bfloat16(f);
    return *(unsigned short*)&h;
}
static __device__ __forceinline__ unsigned pack2bf(float a, float b) {
    return (unsigned)f2bfbits(a) | ((unsigned)f2bfbits(b) << 16);
}
static __device__ __forceinline__ f32x4 mfma16x16x32(ushort8_t a, ushort8_t b, f32x4 c) {
    return __builtin_amdgcn_mfma_f32_16x16x32_bf16(
        __builtin_bit_cast(bf16x8, a), __builtin_bit_cast(bf16x8, b), c, 0, 0, 0);
}

// ---------------------------------------------------------------- setup ----
__global__ void setup_kernel(const float* __restrict__ wq, const float* __restrict__ bq,
                             const float* __restrict__ wk,
                             const float* __restrict__ rel_h, const float* __restrict__ rel_w,
                             const float* __restrict__ wv, const float* __restrict__ bvp,
                             const float* __restrict__ gamma, const float* __restrict__ beta,
                             const float* __restrict__ mean, const float* __restrict__ var,
                             const float* __restrict__ fc1w,
                             char* __restrict__ ws)
{
    __hip_bfloat16* GA  = (__hip_bfloat16*)(ws + OFF_G);
    __hip_bfloat16* WA  = (__hip_bfloat16*)(ws + OFF_WVT);
    float*          Rm  = (float*)(ws + OFF_RT);
    float*          BnS = (float*)(ws + OFF_BNS);
    float*          Bi2 = (float*)(ws + OFF_BNB);
    __hip_bfloat16* W1  = (__hip_bfloat16*)(ws + OFF_W1);

    int idx = blockIdx.x * blockDim.x + threadIdx.x;
    if (idx < 16384) {
        int c = idx >> 7, a = idx & 127;     // GA[c][a] = sum_o wq[o,a]*wk[o,c]
        float s = 0.f;
        for (int o = 0; o < 128; ++o) s += wq[o * 128 + a] * wk[o * 128 + c];
        GA[idx] = __float2bfloat16(s);
    } else if (idx < 32768) {
        int t = idx - 16384;                 // WA[oc][j] = wv[oc][j] * inv[oc]
        int oc = t >> 7;
        float inv = gamma[oc] * rsqrtf(var[oc] + 1e-5f);
        WA[t] = __float2bfloat16(wv[t] * inv);
    } else if (idx < 34304) {
        int t = idx - 32768;                 // Rm[c][i]
        int c = t / 12, i = t - c * 12;
        float s = 0.f;
        for (int o = 0; o < 128; ++o)
            s += bq[o] * wk[o * 128 + c] + wq[o * 128 + c] * (rel_h[o * 12 + i] + rel_w[o]);
        Rm[t] = s;
    } else if (idx < 34432) {
        int c = idx - 34304;
        float inv = gamma[c] * rsqrtf(var[c] + 1e-5f);
        BnS[c] = inv;
        Bi2[c] = bvp[c] * inv + beta[c] - mean[c] * inv;
    } else if (idx < 300672) {
        int t = idx - 34432;                 // W1[h][k] = fc1w[h][k] (identity order)
        int h = t / 1280, k = t - h * 1280;
        W1[t] = (h < 200) ? __float2bfloat16(fc1w[h * 1280 + k])
                          : __float2bfloat16(0.f);
    } else if (idx < 300736) {
        // ---- MFMA fragment-layout probe (one full wave) ----
        int l = idx - 300672;
        int m = l & 15, g = l >> 4;
        ushort8_t av, bv8;
        for (int j = 0; j < 8; ++j) {
            int k = g * 8 + j;
            float aval = (float)(((m * 5 + k * 3) % 7) - 3);
            float bval = (float)(((k * 11 + m * 2) % 5) - 2);
            av[j]  = (unsigned short)(__float_as_uint(aval) >> 16);
            bv8[j] = (unsigned short)(__float_as_uint(bval) >> 16);
        }
        f32x4 zero = {0.f, 0.f, 0.f, 0.f};
        f32x4 d = mfma16x16x32(av, bv8, zero);
        bool ok = true;
        int col = l & 15;
        for (int r = 0; r < 4; ++r) {
            int row = g * 4 + r;
            float ref = 0.f;
            for (int k = 0; k < 32; ++k)
                ref += (float)(((row * 5 + k * 3) % 7) - 3) *
                       (float)(((k * 11 + col * 2) % 5) - 2);
            if (d[r] != ref) ok = false;
        }
        unsigned long long ball = __ballot(ok ? 1 : 0);
        if (l == 0) *(int*)(ws + OFF_FLAG) = (ball == ~0ull) ? 1 : 0;
    }
}

// ------------------------------------------------- MFMA attention stage ----
// 2-barrier structure. Per group (4 batches, wave w owns batch w):
//   [wave loads OWN batch x -> own Xb rows]  barB
//   [s1: t'=G^T X+R -> TZ, Y=Wv'X -> YY  (cross-batch, 2 oc-tiles/wave)] bar2
//   [wave-local tail on OWN batch: s2 -> softmax -> P-transpose (512B
//    wave-private LDS, lgkmcnt+sched_barrier) -> s3 over all 8 oc-tiles ->
//    reg-pool -> u32 stores]  (no gang sync)
// barB also orders prev-group tails vs s1's TZ/YY overwrite (tail precedes
// each wave's next x-load in program order). Own-Xb rows: only own wave
// writes/reads them across groups -> no barrier needed there.
// LDS 51200 B -> 3 blocks/CU. bounds(256,3): R10/R11 lesson — (256,4) makes
// the allocator target 64 VGPR and spill; tripwire: VGPR>64, FETCH ~155MB.
#define XB_H   0        // u16: Xb [64][128] chunk-XOR swizzled (X^T per batch)
#define TZ_H   8192     // u16: t' [64][128] swizzled transpose
#define YY_H   16384    // u16: Y  [4][128][16]
#define PT_H   24576    // u16: P-transpose scratch [4][256] (wave-private)

__launch_bounds__(256, 3)
__global__ void attn_kernel(const float* __restrict__ x,
                            const char* __restrict__ ws,
                            __hip_bfloat16* __restrict__ pooled)
{
    __shared__ __align__(16) char lds[51200];
    unsigned short* LH = (unsigned short*)lds;

    const int tid = threadIdx.x;
    const int w = tid >> 6, l = tid & 63, g = l >> 4, lr = l & 15;

    const unsigned short* GA = (const unsigned short*)(ws + OFF_G);
    const unsigned short* WA = (const unsigned short*)(ws + OFF_WVT);
    const float* Rm  = (const float*)(ws + OFF_RT);
    const float* Bi2 = (const float*)(ws + OFF_BNB);

    // persistent per-wave weight fragments (2 oc-tiles) + Rm regs + bias2[8]
    ushort8_t gfrag[2][4], wfrag[2][4];
    float rm[2][4], b2[8];
    #pragma unroll
    for (int mi = 0; mi < 2; ++mi) {
        int mt = w + mi * 4;
        #pragma unroll
        for (int kt = 0; kt < 4; ++kt) {
            gfrag[mi][kt] = *(const ushort8_t*)(GA + (mt * 16 + lr) * 128 + kt * 32 + g * 8);
            wfrag[mi][kt] = *(const ushort8_t*)(WA + (mt * 16 + lr) * 128 + kt * 32 + g * 8);
        }
        #pragma unroll
        for (int r = 0; r < 4; ++r)
            rm[mi][r] = (lr < 12) ? Rm[(mt * 16 + g * 4 + r) * 12 + lr] : 0.f;
    }
    #pragma unroll
    for (int mt = 0; mt < 8; ++mt) b2[mt] = Bi2[mt * 16 + lr];

    const ushort8_t zero8 = {0, 0, 0, 0, 0, 0, 0, 0};
    // zero Xb pad rows (n = bb*16 + 12..15) once — DO NOT REMOVE (R8 bug:
    // uninitialized LDS can be NaN; NaN*0 leaks through output masking)
    {
        int rr = tid >> 4, bb = rr >> 2, sub = rr & 3;
        int n = bb * 16 + 12 + sub;
        *(ushort8_t*)(LH + XB_H + n * 128 + (tid & 15) * 8) = zero8;
    }

    for (int grp = 0; grp < 4; ++grp) {
        const int b = blockIdx.x * 16 + grp * 4 + w;   // own batch

        // ---- own-batch x load: lane l -> channels 2l, 2l+1 (24 floats)
        {
            const f32x4* xp = (const f32x4*)(x + (size_t)b * 1536 + l * 24);
            f32x4 q0 = xp[0], q1 = xp[1], q2 = xp[2], q3 = xp[3], q4 = xp[4], q5 = xp[5];
            const int c0 = 2 * l, c1 = 2 * l + 1;
            float v0[12] = {q0[0], q0[1], q0[2], q0[3], q1[0], q1[1], q1[2], q1[3],
                            q2[0], q2[1], q2[2], q2[3]};
            float v1[12] = {q3[0], q3[1], q3[2], q3[3], q4[0], q4[1], q4[2], q4[3],
                            q5[0], q5[1], q5[2], q5[3]};
            #pragma unroll
            for (int i = 0; i < 12; ++i) {
                int row = XB_H + (w * 16 + i) * 128;
                LH[row + (((c0 >> 3) ^ i) << 3) + (c0 & 7)] = f2bfbits(v0[i]);
                LH[row + (((c1 >> 3) ^ i) << 3) + (c1 & 7)] = f2bfbits(v1[i]);
            }
        }
        __syncthreads();   // barB: all Xb ready; prev tails done vs TZ/YY

        // ---- s1: read Xb fragments once; t' -> TZ, Y -> YY (2 oc-tiles/wave)
        #pragma unroll
        for (int nt = 0; nt < 4; ++nt) {
            int n = nt * 16 + lr;
            ushort8_t bf[4];
            #pragma unroll
            for (int kt = 0; kt < 4; ++kt)
                bf[kt] = *(const ushort8_t*)(LH + XB_H + n * 128 + ((((kt << 2) + g) ^ lr) << 3));
            #pragma unroll
            for (int mi = 0; mi < 2; ++mi) {
                f32x4 acc = {0.f, 0.f, 0.f, 0.f};
                f32x4 ya  = {0.f, 0.f, 0.f, 0.f};
                #pragma unroll
                for (int kt = 0; kt < 4; ++kt) {
                    acc = mfma16x16x32(gfrag[mi][kt], bf[kt], acc);
                    ya  = mfma16x16x32(wfrag[mi][kt], bf[kt], ya);
                }
                int ocb = (w + mi * 4) * 16 + g * 4;
                float v0 = acc[0] + rm[mi][0];
                float v1 = acc[1] + rm[mi][1];
                float v2 = acc[2] + rm[mi][2];
                float v3 = acc[3] + rm[mi][3];
                unsigned off = TZ_H + n * 128 + (((ocb >> 3) ^ lr) << 3) + ((g & 1) << 2);
                *(unsigned*)(LH + off)     = pack2bf(v0, v1);
                *(unsigned*)(LH + off + 2) = pack2bf(v2, v3);
                #pragma unroll
                for (int r = 0; r < 4; ++r)
                    LH[YY_H + nt * 2048 + (ocb + r) * 16 + lr] = f2bfbits(ya[r]);
            }
        }
        __syncthreads();   // bar2: t' + Y visible to all waves

        // ---- wave-local tail on own batch ----
        // s2: S = t'^T X
        f32x4 s = {0.f, 0.f, 0.f, 0.f};
        {
            int n = w * 16 + lr;
            #pragma unroll
            for (int kt = 0; kt < 4; ++kt) {
                unsigned ch = (((kt << 2) + g) ^ lr) << 3;
                ushort8_t af  = *(const ushort8_t*)(LH + TZ_H + n * 128 + ch);
                ushort8_t bfx = *(const ushort8_t*)(LH + XB_H + n * 128 + ch);
                s = mfma16x16x32(af, bfx, s);
            }
        }
        // softmax (rows i = g*4+r, col j = lr)
        {
            bool jv = (lr < 12);
            float mx[4], ev[4], sum[4];
            #pragma unroll
            for (int r = 0; r < 4; ++r) mx[r] = jv ? s[r] : -3.0e38f;
            #pragma unroll
            for (int d = 1; d < 16; d <<= 1) {
                #pragma unroll
                for (int r = 0; r < 4; ++r) mx[r] = fmaxf(mx[r], __shfl_xor(mx[r], d));
            }
            #pragma unroll
            for (int r = 0; r < 4; ++r) { ev[r] = jv ? __expf(s[r] - mx[r]) : 0.f; sum[r] = ev[r]; }
            #pragma unroll
            for (int d = 1; d < 16; d <<= 1) {
                #pragma unroll
                for (int r = 0; r < 4; ++r) sum[r] += __shfl_xor(sum[r], d);
            }
            // P-transpose scratch (wave-private 512 B): P[i][j] -> A-fragment
            #pragma unroll
            for (int r = 0; r < 4; ++r)
                LH[PT_H + w * 256 + (g * 4 + r) * 16 + lr] = f2bfbits(ev[r] / sum[r]);
        }
        asm volatile("s_waitcnt lgkmcnt(0)" ::: "memory");   // own-wave LDS RAW
        __builtin_amdgcn_sched_barrier(0);                    // rule #18 fence

        // s3: out^T = P . Y^T + bias2 over all 8 oc-tiles of own batch
        ushort8_t paf = (g < 2)
            ? *(const ushort8_t*)(LH + PT_H + w * 256 + lr * 16 + g * 8) : zero8;
        #pragma unroll
        for (int mt = 0; mt < 8; ++mt) {
            ushort8_t bfy = (g < 2)
                ? *(const ushort8_t*)(LH + YY_H + w * 2048 + (mt * 16 + lr) * 16 + g * 8)
                : zero8;
            float bias = b2[mt];
            f32x4 o = {bias, bias, bias, bias};
            o = mfma16x16x32(paf, bfy, o);
            float s0 = __shfl_down(o[0], 16);
            float s1 = __shfl_down(o[1], 16);
            float p0 = fmaxf(fmaxf(fmaxf(o[0], o[1]), o[2]), 0.f);
            float p1 = fmaxf(fmaxf(fmaxf(o[1], o[2]), o[3]), 0.f);
            float p2 = fmaxf(fmaxf(fmaxf(o[2], o[3]), s0), 0.f);
            float p3 = fmaxf(fmaxf(fmaxf(o[3], s0), s1), 0.f);
            unsigned* pw = (unsigned*)((unsigned short*)pooled
                         + (size_t)b * 1280 + (mt * 16 + lr) * 10 + g * 4);
            if (g < 2) { pw[0] = pack2bf(p0, p1); pw[1] = pack2bf(p2, p3); }
            else if (g == 2) pw[0] = pack2bf(p0, p1);
        }
        // no end barrier: own Xb rows are only touched by this wave; TZ/YY/PT
        // overwrites happen in s1(g+1), which all waves reach only after
        // barB(g+1), i.e. after every wave finished this tail.
    }
}

// ----------------------------------------------------------- fc1+fc2 ----
__launch_bounds__(512, 1)
__global__ void fc_kernel(const __hip_bfloat16* __restrict__ pooled_bf,
                          const char* __restrict__ ws,
                          const float* __restrict__ fc1b,
                          const float* __restrict__ fc2w, const float* __restrict__ fc2b,
                          float* __restrict__ out)
{
    __shared__ char smem[54272];
    const int tid = threadIdx.x;
    const int b0  = blockIdx.x * 128;
    const unsigned short* P  = (const unsigned short*)pooled_bf;
    const unsigned short* W1 = (const unsigned short*)(ws + OFF_W1);
    unsigned short* hid = (unsigned short*)smem;
    const int flag = *(const int*)(ws + OFF_FLAG);

    if (flag) {
        const int l = tid & 63, w = tid >> 6;
        const int lrow = l & 15, g = l >> 4;
        f32x4 acc[13];
        #pragma unroll
        for (int nt = 0; nt < 13; ++nt) acc[nt] = (f32x4){0.f, 0.f, 0.f, 0.f};

        const int pr = tid >> 2, pc = tid & 3;
        const size_t pbase = (size_t)(b0 + pr) * 1280 + pc * 8;
        const int i1 = tid, i2 = tid + 512;
        const int h1 = i1 >> 2, c1 = i1 & 3;
        const int h2 = i2 >> 2, c2 = i2 & 3;
        const bool has2 = (i2 < 832);

        ushort8_t pReg, w1a, w1b;
        pReg = *(const ushort8_t*)(P + pbase);
        w1a  = *(const ushort8_t*)(W1 + (size_t)h1 * 1280 + c1 * 8);
        if (has2) w1b = *(const ushort8_t*)(W1 + (size_t)h2 * 1280 + c2 * 8);
        *(ushort8_t*)(smem + tid * 16) = pReg;
        *(ushort8_t*)(smem + 8192 + i1 * 16) = w1a;
        if (has2) *(ushort8_t*)(smem + 8192 + i2 * 16) = w1b;
        __syncthreads();

        int cur = 0;
        for (int ks = 0; ks < 40; ++ks) {
            if (ks + 1 < 40) {
                pReg = *(const ushort8_t*)(P + pbase + (size_t)(ks + 1) * 32);
                w1a  = *(const ushort8_t*)(W1 + (size_t)h1 * 1280 + (ks + 1) * 32 + c1 * 8);
                if (has2) w1b = *(const ushort8_t*)(W1 + (size_t)h2 * 1280 + (ks + 1) * 32 + c2 * 8);
            }
            const unsigned short* Pt = (const unsigned short*)(smem + (cur ? 21504 : 0));
            const unsigned short* Wt = (const unsigned short*)(smem + (cur ? 29696 : 8192));
            ushort8_t A = *(const ushort8_t*)(Pt + (w * 16 + lrow) * 32 + g * 8);
            #pragma unroll
            for (int nt = 0; nt < 13; ++nt) {
                ushort8_t Bf = *(const ushort8_t*)(Wt + (nt * 16 + lrow) * 32 + g * 8);
                acc[nt] = mfma16x16x32(A, Bf, acc[nt]);
            }
            __syncthreads();
            if (ks + 1 < 40) {
                char* dp = smem + ((cur ^ 1) ? 21504 : 0);
                char* dw = smem + ((cur ^ 1) ? 29696 : 8192);
                *(ushort8_t*)(dp + tid * 16) = pReg;
                *(ushort8_t*)(dw + i1 * 16) = w1a;
                if (has2) *(ushort8_t*)(dw + i2 * 16) = w1b;
            }
            __syncthreads();
            cur ^= 1;
        }
        #pragma unroll
        for (int nt = 0; nt < 13; ++nt) {
            int h = nt * 16 + lrow;
            float bias = (h < 200) ? fc1b[h] : 0.f;
            #pragma unroll
            for (int r = 0; r < 4; ++r) {
                float v = fmaxf(acc[nt][r] + bias, 0.f);
                int row = w * 16 + g * 4 + r;
                hid[row * 210 + h] = f2bfbits(v);
            }
        }
    } else {
        for (int i = tid; i < 128 * 200; i += 512) {
            int bb = i / 200, h = i - bb * 200;
            float s = fc1b[h];
            const unsigned short* prow = P + (size_t)(b0 + bb) * 1280;
            const unsigned short* wrow = W1 + (size_t)h * 1280;
            for (int j = 0; j < 1280; ++j)
                s += bfbits2f(prow[j]) * bfbits2f(wrow[j]);
            hid[bb * 210 + h] = f2bfbits(fmaxf(s, 0.f));
        }
    }
    __syncthreads();

    if (tid < 256) {
        int bb = tid >> 1, o = tid & 1;
        float s = fc2b[o];
        const unsigned short* hp = hid + bb * 210;
        const float* wp = fc2w + o * 200;
        #pragma unroll 8
        for (int j = 0; j < 200; ++j)
            s += bfbits2f(hp[j]) * wp[j];
        out[(size_t)(b0 + bb) * 2 + o] = 1.f / (1.f + __expf(-s));
    }
}

// ------------------------------------------------------------- launch ----
extern "C" void kernel_launch(void* const* d_in, const int* in_sizes, int n_in,
                              void* d_out, int out_size, void* d_ws, size_t ws_size,
                              hipStream_t stream)
{
    const float* x     = (const float*)d_in[0];
    const float* wq    = (const float*)d_in[1];
    const float* bq    = (const float*)d_in[2];
    const float* wk    = (const float*)d_in[3];
    // d_in[4] = bk: cancels under softmax row-invariance — unused.
    const float* wv    = (const float*)d_in[5];
    const float* bv    = (const float*)d_in[6];
    const float* rel_h = (const float*)d_in[7];
    const float* rel_w = (const float*)d_in[8];
    const float* gamma = (const float*)d_in[9];
    const float* beta  = (const float*)d_in[10];
    const float* mean  = (const float*)d_in[11];
    const float* var   = (const float*)d_in[12];
    const float* fc1w  = (const float*)d_in[13];
    const float* fc1b  = (const float*)d_in[14];
    const float* fc2w  = (const float*)d_in[15];
    const float* fc2b  = (const float*)d_in[16];

    char* ws = (char*)d_ws;
    __hip_bfloat16* pooled = (__hip_bfloat16*)(ws + OFF_P);
    float* out = (float*)d_out;

    setup_kernel<<<1175, 256, 0, stream>>>(wq, bq, wk, rel_h, rel_w, wv, bv,
                                           gamma, beta, mean, var, fc1w, ws);
    attn_kernel<<<2048, 256, 0, stream>>>(x, ws, pooled);
    fc_kernel<<<256, 512, 0, stream>>>(pooled, ws, fc1b, fc2w, fc2b, out);
}

// Round 15
// 220.282 us; speedup vs baseline: 1.0499x; 1.0499x over previous
//
#include <hip/hip_runtime.h>
#include <hip/hip_bf16.h>

// Workspace byte offsets
#define OFF_G    0u        // bf16 [128][128]  GA[oc][ic] = sum_o wq[o,ic]*wk[o,oc]
#define OFF_WVT  32768u    // bf16 [128][128]  WA[oc][j] = wv[oc][j] * bns[oc]  (BN-folded)
#define OFF_RT   65536u    // f32  [128][12]   Rm[c][i]
#define OFF_BNS  71680u    // f32  [128]       (unused by attn now)
#define OFF_BNB  72192u    // f32  [128]       bias2 = bv*bns + beta - mean*bns
#define OFF_FLAG 72704u    // int: 1 if MFMA fragment-layout probe verified
#define OFF_W1   72768u    // bf16 [208][1280] fc1 weights, original k = c*10+m order
#define OFF_P    605248u   // bf16 [32768][1280] pooled, original k = c*10+m order

typedef __attribute__((ext_vector_type(8))) unsigned short ushort8_t;
typedef __attribute__((ext_vector_type(8))) __bf16 bf16x8;
typedef __attribute__((ext_vector_type(4))) float f32x4;

static __device__ __forceinline__ float bfbits2f(unsigned short u) {
    return __uint_as_float(((unsigned)u) << 16);
}
static __device__ __forceinline__ unsigned short f2bfbits(float f) {
    __hip_bfloat16 h = __float2bfloat16(f);
    return *(unsigned short*)&h;
}
static __device__ __forceinline__ unsigned pack2bf(float a, float b) {
    return (unsigned)f2bfbits(a) | ((unsigned)f2bfbits(b) << 16);
}
static __device__ __forceinline__ f32x4 mfma16x16x32(ushort8_t a, ushort8_t b, f32x4 c) {
    return __builtin_amdgcn_mfma_f32_16x16x32_bf16(
        __builtin_bit_cast(bf16x8, a), __builtin_bit_cast(bf16x8, b), c, 0, 0, 0);
}

// ---------------------------------------------------------------- setup ----
__global__ void setup_kernel(const float* __restrict__ wq, const float* __restrict__ bq,
                             const float* __restrict__ wk,
                             const float* __restrict__ rel_h, const float* __restrict__ rel_w,
                             const float* __restrict__ wv, const float* __restrict__ bvp,
                             const float* __restrict__ gamma, const float* __restrict__ beta,
                             const float* __restrict__ mean, const float* __restrict__ var,
                             const float* __restrict__ fc1w,
                             char* __restrict__ ws)
{
    __hip_bfloat16* GA  = (__hip_bfloat16*)(ws + OFF_G);
    __hip_bfloat16* WA  = (__hip_bfloat16*)(ws + OFF_WVT);
    float*          Rm  = (float*)(ws + OFF_RT);
    float*          BnS = (float*)(ws + OFF_BNS);
    float*          Bi2 = (float*)(ws + OFF_BNB);
    __hip_bfloat16* W1  = (__hip_bfloat16*)(ws + OFF_W1);

    int idx = blockIdx.x * blockDim.x + threadIdx.x;
    if (idx < 16384) {
        int c = idx >> 7, a = idx & 127;     // GA[c][a] = sum_o wq[o,a]*wk[o,c]
        float s = 0.f;
        for (int o = 0; o < 128; ++o) s += wq[o * 128 + a] * wk[o * 128 + c];
        GA[idx] = __float2bfloat16(s);
    } else if (idx < 32768) {
        int t = idx - 16384;                 // WA[oc][j] = wv[oc][j] * inv[oc]
        int oc = t >> 7;
        float inv = gamma[oc] * rsqrtf(var[oc] + 1e-5f);
        WA[t] = __float2bfloat16(wv[t] * inv);
    } else if (idx < 34304) {
        int t = idx - 32768;                 // Rm[c][i]
        int c = t / 12, i = t - c * 12;
        float s = 0.f;
        for (int o = 0; o < 128; ++o)
            s += bq[o] * wk[o * 128 + c] + wq[o * 128 + c] * (rel_h[o * 12 + i] + rel_w[o]);
        Rm[t] = s;
    } else if (idx < 34432) {
        int c = idx - 34304;
        float inv = gamma[c] * rsqrtf(var[c] + 1e-5f);
        BnS[c] = inv;
        Bi2[c] = bvp[c] * inv + beta[c] - mean[c] * inv;
    } else if (idx < 300672) {
        int t = idx - 34432;                 // W1[h][k] = fc1w[h][k] (identity order)
        int h = t / 1280, k = t - h * 1280;
        W1[t] = (h < 200) ? __float2bfloat16(fc1w[h * 1280 + k])
                          : __float2bfloat16(0.f);
    } else if (idx < 300736) {
        // ---- MFMA fragment-layout probe (one full wave) ----
        int l = idx - 300672;
        int m = l & 15, g = l >> 4;
        ushort8_t av, bv8;
        for (int j = 0; j < 8; ++j) {
            int k = g * 8 + j;
            float aval = (float)(((m * 5 + k * 3) % 7) - 3);
            float bval = (float)(((k * 11 + m * 2) % 5) - 2);
            av[j]  = (unsigned short)(__float_as_uint(aval) >> 16);
            bv8[j] = (unsigned short)(__float_as_uint(bval) >> 16);
        }
        f32x4 zero = {0.f, 0.f, 0.f, 0.f};
        f32x4 d = mfma16x16x32(av, bv8, zero);
        bool ok = true;
        int col = l & 15;
        for (int r = 0; r < 4; ++r) {
            int row = g * 4 + r;
            float ref = 0.f;
            for (int k = 0; k < 32; ++k)
                ref += (float)(((row * 5 + k * 3) % 7) - 3) *
                       (float)(((k * 11 + col * 2) % 5) - 2);
            if (d[r] != ref) ok = false;
        }
        unsigned long long ball = __ballot(ok ? 1 : 0);
        if (l == 0) *(int*)(ws + OFF_FLAG) = (ball == ~0ull) ? 1 : 0;
    }
}

// ------------------------------------------------- MFMA attention stage ----
// R9 structure EXACTLY (best measured: attn 186 us, 64 VGPR no-spill,
// 4 blocks/CU) + T5 s_setprio(1)/(0) around the two 32-MFMA clusters
// (s1, s2b). T5 mechanism applies: ~3.6 blocks/CU at different phases ->
// scheduler can prefer MFMA-issuing waves over glue-issuing waves.
// R14 lesson (catalog m240): do NOT hand-write v_cvt_pk_bf16_f32 — broke
// correctness and is measured slower than the scalar cast anyway.
#define XB_H   0        // Xb  [64][128] u16, chunk-XOR swizzled (X^T per batch)
#define TZY_H  8192     // u16: t' [64][128] swizzled; after bar3: Y [4][128][16]
#define PP_H   16384    // u16: P [4][16][16] (row m, col n; zero-padded)

__launch_bounds__(256, 4)
__global__ void attn_kernel(const float* __restrict__ x,
                            const char* __restrict__ ws,
                            __hip_bfloat16* __restrict__ pooled)
{
    __shared__ __align__(16) char lds[34816];
    unsigned short* LH = (unsigned short*)lds;

    const int tid = threadIdx.x;
    const int w = tid >> 6, l = tid & 63, g = l >> 4, lr = l & 15;

    const unsigned short* GA = (const unsigned short*)(ws + OFF_G);
    const unsigned short* WA = (const unsigned short*)(ws + OFF_WVT);
    const float* Rm  = (const float*)(ws + OFF_RT);
    const float* Bi2 = (const float*)(ws + OFF_BNB);

    // persistent per-wave weight fragments + per-lane bias + Rm registers
    ushort8_t gfrag[2][4], wfrag[2][4];
    float bias2v[2], rm[2][4];
    #pragma unroll
    for (int mi = 0; mi < 2; ++mi) {
        int mt = w + mi * 4;
        #pragma unroll
        for (int kt = 0; kt < 4; ++kt) {
            gfrag[mi][kt] = *(const ushort8_t*)(GA + (mt * 16 + lr) * 128 + kt * 32 + g * 8);
            wfrag[mi][kt] = *(const ushort8_t*)(WA + (mt * 16 + lr) * 128 + kt * 32 + g * 8);
        }
        bias2v[mi] = Bi2[mt * 16 + lr];
        #pragma unroll
        for (int r = 0; r < 4; ++r)
            rm[mi][r] = (lr < 12) ? Rm[(mt * 16 + g * 4 + r) * 12 + lr] : 0.f;
    }

    const ushort8_t zero8 = {0, 0, 0, 0, 0, 0, 0, 0};
    // zero the pad rows (n = bb*16 + 12..15) of Xb once — DO NOT REMOVE (R8)
    {
        int rr = tid >> 4, bb = rr >> 2, sub = rr & 3;
        int n = bb * 16 + 12 + sub;
        *(ushort8_t*)(LH + XB_H + n * 128 + (tid & 15) * 8) = zero8;
    }

    const int c = tid & 127, bh = tid >> 7;   // x-load mapping

    for (int grp = 0; grp < 4; ++grp) {
        const int b0g = blockIdx.x * 16 + grp * 4;

        // ---- load x, write Xb (swizzled X^T rows n=bl*16+i, rows 0..11 only)
        #pragma unroll
        for (int b2 = 0; b2 < 2; ++b2) {
            int bl = bh * 2 + b2;
            const float4* xp = (const float4*)(x + ((size_t)(b0g + bl) * 128 + c) * 12);
            float4 xa = xp[0], xb4 = xp[1], xc4 = xp[2];
            float xv[12] = {xa.x, xa.y, xa.z, xa.w, xb4.x, xb4.y, xb4.z, xb4.w,
                            xc4.x, xc4.y, xc4.z, xc4.w};
            #pragma unroll
            for (int i = 0; i < 12; ++i) {
                int n = bl * 16 + i;
                LH[XB_H + n * 128 + (((c >> 3) ^ i) << 3) + (c & 7)] = f2bfbits(xv[i]);
            }
        }
        __syncthreads();   // bar1: Xb ready; prev-group TZY/PP reads all done

        // ---- s1: t' = G^T X + R(reg)  -> TZ (transposed [n][c], swizzled)
        __builtin_amdgcn_s_setprio(1);
        #pragma unroll
        for (int nt = 0; nt < 4; ++nt) {
            int n = nt * 16 + lr;
            ushort8_t bf[4];
            #pragma unroll
            for (int kt = 0; kt < 4; ++kt)
                bf[kt] = *(const ushort8_t*)(LH + XB_H + n * 128 + ((((kt << 2) + g) ^ lr) << 3));
            #pragma unroll
            for (int mi = 0; mi < 2; ++mi) {
                f32x4 acc = {0.f, 0.f, 0.f, 0.f};
                #pragma unroll
                for (int kt = 0; kt < 4; ++kt) acc = mfma16x16x32(gfrag[mi][kt], bf[kt], acc);
                int ocb = (w + mi * 4) * 16 + g * 4;
                float v0 = acc[0] + rm[mi][0];
                float v1 = acc[1] + rm[mi][1];
                float v2 = acc[2] + rm[mi][2];
                float v3 = acc[3] + rm[mi][3];
                unsigned off = TZY_H + n * 128 + (((ocb >> 3) ^ lr) << 3) + ((g & 1) << 2);
                *(unsigned*)(LH + off)     = pack2bf(v0, v1);
                *(unsigned*)(LH + off + 2) = pack2bf(v2, v3);
            }
        }
        __builtin_amdgcn_s_setprio(0);
        __syncthreads();   // bar2: t' ready

        // ---- s2: S = t'^T X (wave's own batch), softmax rows -> PP[m][n]
        {
            int n = w * 16 + lr;
            f32x4 s = {0.f, 0.f, 0.f, 0.f};
            #pragma unroll
            for (int kt = 0; kt < 4; ++kt) {
                unsigned ch = (((kt << 2) + g) ^ lr) << 3;
                ushort8_t af = *(const ushort8_t*)(LH + TZY_H + n * 128 + ch);
                ushort8_t bf = *(const ushort8_t*)(LH + XB_H + n * 128 + ch);
                s = mfma16x16x32(af, bf, s);
            }
            bool jv = (lr < 12);
            float mx[4], ev[4], sum[4];
            #pragma unroll
            for (int r = 0; r < 4; ++r) mx[r] = jv ? s[r] : -3.0e38f;
            #pragma unroll
            for (int d = 1; d < 16; d <<= 1) {
                #pragma unroll
                for (int r = 0; r < 4; ++r) mx[r] = fmaxf(mx[r], __shfl_xor(mx[r], d));
            }
            #pragma unroll
            for (int r = 0; r < 4; ++r) { ev[r] = jv ? __expf(s[r] - mx[r]) : 0.f; sum[r] = ev[r]; }
            #pragma unroll
            for (int d = 1; d < 16; d <<= 1) {
                #pragma unroll
                for (int r = 0; r < 4; ++r) sum[r] += __shfl_xor(sum[r], d);
            }
            #pragma unroll
            for (int r = 0; r < 4; ++r)
                LH[PP_H + w * 256 + (g * 4 + r) * 16 + lr] = f2bfbits(ev[r] / sum[r]);
        }
        __syncthreads();   // bar3: t' reads done -> TZ space reusable as Y

        // ---- s2b: Y = Wv' X  -> Y[bb][oc][i] (over TZ space)
        __builtin_amdgcn_s_setprio(1);
        #pragma unroll
        for (int nt = 0; nt < 4; ++nt) {
            int n = nt * 16 + lr;
            ushort8_t bf[4];
            #pragma unroll
            for (int kt = 0; kt < 4; ++kt)
                bf[kt] = *(const ushort8_t*)(LH + XB_H + n * 128 + ((((kt << 2) + g) ^ lr) << 3));
            #pragma unroll
            for (int mi = 0; mi < 2; ++mi) {
                f32x4 acc = {0.f, 0.f, 0.f, 0.f};
                #pragma unroll
                for (int kt = 0; kt < 4; ++kt) acc = mfma16x16x32(wfrag[mi][kt], bf[kt], acc);
                int ocb = (w + mi * 4) * 16 + g * 4;
                #pragma unroll
                for (int r = 0; r < 4; ++r)
                    LH[TZY_H + nt * 2048 + (ocb + r) * 16 + lr] = f2bfbits(acc[r]);
            }
        }
        __builtin_amdgcn_s_setprio(0);
        __syncthreads();   // bar4: Y + PP ready

        // ---- s3: out^T = P . Y^T + bias2; ReLU+pool(3) in regs; u32 stores
        // pooled layout: [b][c*10 + m] -> 20 contiguous B per (b,oc).
        #pragma unroll
        for (int mi = 0; mi < 2; ++mi) {
            int mt = w + mi * 4;
            float bias = bias2v[mi];
            #pragma unroll
            for (int bb = 0; bb < 4; ++bb) {
                ushort8_t af = (g < 2)
                    ? *(const ushort8_t*)(LH + PP_H + bb * 256 + lr * 16 + g * 8) : zero8;
                ushort8_t bfy = (g < 2)
                    ? *(const ushort8_t*)(LH + TZY_H + bb * 2048 + (mt * 16 + lr) * 16 + g * 8)
                    : zero8;
                f32x4 o = {bias, bias, bias, bias};
                o = mfma16x16x32(af, bfy, o);
                float s0 = __shfl_down(o[0], 16);
                float s1 = __shfl_down(o[1], 16);
                float p0 = fmaxf(fmaxf(fmaxf(o[0], o[1]), o[2]), 0.f);
                float p1 = fmaxf(fmaxf(fmaxf(o[1], o[2]), o[3]), 0.f);
                float p2 = fmaxf(fmaxf(fmaxf(o[2], o[3]), s0), 0.f);
                float p3 = fmaxf(fmaxf(fmaxf(o[3], s0), s1), 0.f);
                unsigned* pw = (unsigned*)((unsigned short*)pooled
                             + (size_t)(b0g + bb) * 1280 + (mt * 16 + lr) * 10 + g * 4);
                if (g < 2) { pw[0] = pack2bf(p0, p1); pw[1] = pack2bf(p2, p3); }
                else if (g == 2) pw[0] = pack2bf(p0, p1);
            }
        }
        // no end barrier: next iter's Xb write touches only rows bl*16+0..11,
        // disjoint from everything read after bar4; bar1 orders the rest.
    }
}

// ----------------------------------------------------------- fc1+fc2 ----
__launch_bounds__(512, 1)
__global__ void fc_kernel(const __hip_bfloat16* __restrict__ pooled_bf,
                          const char* __restrict__ ws,
                          const float* __restrict__ fc1b,
                          const float* __restrict__ fc2w, const float* __restrict__ fc2b,
                          float* __restrict__ out)
{
    __shared__ char smem[54272];
    const int tid = threadIdx.x;
    const int b0  = blockIdx.x * 128;
    const unsigned short* P  = (const unsigned short*)pooled_bf;
    const unsigned short* W1 = (const unsigned short*)(ws + OFF_W1);
    unsigned short* hid = (unsigned short*)smem;
    const int flag = *(const int*)(ws + OFF_FLAG);

    if (flag) {
        const int l = tid & 63, w = tid >> 6;
        const int lrow = l & 15, g = l >> 4;
        f32x4 acc[13];
        #pragma unroll
        for (int nt = 0; nt < 13; ++nt) acc[nt] = (f32x4){0.f, 0.f, 0.f, 0.f};

        const int pr = tid >> 2, pc = tid & 3;
        const size_t pbase = (size_t)(b0 + pr) * 1280 + pc * 8;
        const int i1 = tid, i2 = tid + 512;
        const int h1 = i1 >> 2, c1 = i1 & 3;
        const int h2 = i2 >> 2, c2 = i2 & 3;
        const bool has2 = (i2 < 832);

        ushort8_t pReg, w1a, w1b;
        pReg = *(const ushort8_t*)(P + pbase);
        w1a  = *(const ushort8_t*)(W1 + (size_t)h1 * 1280 + c1 * 8);
        if (has2) w1b = *(const ushort8_t*)(W1 + (size_t)h2 * 1280 + c2 * 8);
        *(ushort8_t*)(smem + tid * 16) = pReg;
        *(ushort8_t*)(smem + 8192 + i1 * 16) = w1a;
        if (has2) *(ushort8_t*)(smem + 8192 + i2 * 16) = w1b;
        __syncthreads();

        int cur = 0;
        for (int ks = 0; ks < 40; ++ks) {
            if (ks + 1 < 40) {
                pReg = *(const ushort8_t*)(P + pbase + (size_t)(ks + 1) * 32);
                w1a  = *(const ushort8_t*)(W1 + (size_t)h1 * 1280 + (ks + 1) * 32 + c1 * 8);
                if (has2) w1b = *(const ushort8_t*)(W1 + (size_t)h2 * 1280 + (ks + 1) * 32 + c2 * 8);
            }
            const unsigned short* Pt = (const unsigned short*)(smem + (cur ? 21504 : 0));
            const unsigned short* Wt = (const unsigned short*)(smem + (cur ? 29696 : 8192));
            ushort8_t A = *(const ushort8_t*)(Pt + (w * 16 + lrow) * 32 + g * 8);
            #pragma unroll
            for (int nt = 0; nt < 13; ++nt) {
                ushort8_t Bf = *(const ushort8_t*)(Wt + (nt * 16 + lrow) * 32 + g * 8);
                acc[nt] = mfma16x16x32(A, Bf, acc[nt]);
            }
            __syncthreads();
            if (ks + 1 < 40) {
                char* dp = smem + ((cur ^ 1) ? 21504 : 0);
                char* dw = smem + ((cur ^ 1) ? 29696 : 8192);
                *(ushort8_t*)(dp + tid * 16) = pReg;
                *(ushort8_t*)(dw + i1 * 16) = w1a;
                if (has2) *(ushort8_t*)(dw + i2 * 16) = w1b;
            }
            __syncthreads();
            cur ^= 1;
        }
        #pragma unroll
        for (int nt = 0; nt < 13; ++nt) {
            int h = nt * 16 + lrow;
            float bias = (h < 200) ? fc1b[h] : 0.f;
            #pragma unroll
            for (int r = 0; r < 4; ++r) {
                float v = fmaxf(acc[nt][r] + bias, 0.f);
                int row = w * 16 + g * 4 + r;
                hid[row * 210 + h] = f2bfbits(v);
            }
        }
    } else {
        for (int i = tid; i < 128 * 200; i += 512) {
            int bb = i / 200, h = i - bb * 200;
            float s = fc1b[h];
            const unsigned short* prow = P + (size_t)(b0 + bb) * 1280;
            const unsigned short* wrow = W1 + (size_t)h * 1280;
            for (int j = 0; j < 1280; ++j)
                s += bfbits2f(prow[j]) * bfbits2f(wrow[j]);
            hid[bb * 210 + h] = f2bfbits(fmaxf(s, 0.f));
        }
    }
    __syncthreads();

    if (tid < 256) {
        int bb = tid >> 1, o = tid & 1;
        float s = fc2b[o];
        const unsigned short* hp = hid + bb * 210;
        const float* wp = fc2w + o * 200;
        #pragma unroll 8
        for (int j = 0; j < 200; ++j)
            s += bfbits2f(hp[j]) * wp[j];
        out[(size_t)(b0 + bb) * 2 + o] = 1.f / (1.f + __expf(-s));
    }
}

// ------------------------------------------------------------- launch ----
extern "C" void kernel_launch(void* const* d_in, const int* in_sizes, int n_in,
                              void* d_out, int out_size, void* d_ws, size_t ws_size,
                              hipStream_t stream)
{
    const float* x     = (const float*)d_in[0];
    const float* wq    = (const float*)d_in[1];
    const float* bq    = (const float*)d_in[2];
    const float* wk    = (const float*)d_in[3];
    // d_in[4] = bk: cancels under softmax row-invariance — unused.
    const float* wv    = (const float*)d_in[5];
    const float* bv    = (const float*)d_in[6];
    const float* rel_h = (const float*)d_in[7];
    const float* rel_w = (const float*)d_in[8];
    const float* gamma = (const float*)d_in[9];
    const float* beta  = (const float*)d_in[10];
    const float* mean  = (const float*)d_in[11];
    const float* var   = (const float*)d_in[12];
    const float* fc1w  = (const float*)d_in[13];
    const float* fc1b  = (const float*)d_in[14];
    const float* fc2w  = (const float*)d_in[15];
    const float* fc2b  = (const float*)d_in[16];

    char* ws = (char*)d_ws;
    __hip_bfloat16* pooled = (__hip_bfloat16*)(ws + OFF_P);
    float* out = (float*)d_out;

    setup_kernel<<<1175, 256, 0, stream>>>(wq, bq, wk, rel_h, rel_w, wv, bv,
                                           gamma, beta, mean, var, fc1w, ws);
    attn_kernel<<<2048, 256, 0, stream>>>(x, ws, pooled);
    fc_kernel<<<256, 512, 0, stream>>>(pooled, ws, fc1b, fc2w, fc2b, out);
}

// Round 16
// 146.854 us; speedup vs baseline: 1.5748x; 1.5000x over previous
//
#include <hip/hip_runtime.h>
#include <hip/hip_bf16.h>

// Workspace byte offsets
#define OFF_G    0u        // bf16 [128][128]  GA[oc][ic] = sum_o wq[o,ic]*wk[o,oc]
#define OFF_WVT  32768u    // bf16 [128][128]  WA[oc][j] = wv[oc][j] * bns[oc]  (BN-folded)
#define OFF_RT   65536u    // f32  [128][12]   Rm[c][i]
#define OFF_BNS  71680u    // f32  [128]       (unused by attn now)
#define OFF_BNB  72192u    // f32  [128]       bias2 = bv*bns + beta - mean*bns
#define OFF_FLAG 72704u    // int: 1 if MFMA fragment-layout probe verified
#define OFF_W1   72768u    // bf16 [208][1280] fc1 weights, original k = c*10+m order
#define OFF_P    605248u   // bf16 [32768][1280] pooled, original k = c*10+m order

typedef __attribute__((ext_vector_type(8))) unsigned short ushort8_t;
typedef __attribute__((ext_vector_type(8))) __bf16 bf16x8;
typedef __attribute__((ext_vector_type(4))) float f32x4;

static __device__ __forceinline__ float bfbits2f(unsigned short u) {
    return __uint_as_float(((unsigned)u) << 16);
}
static __device__ __forceinline__ unsigned short f2bfbits(float f) {
    __hip_bfloat16 h = __float2bfloat16(f);
    return *(unsigned short*)&h;
}
static __device__ __forceinline__ unsigned pack2bf(float a, float b) {
    return (unsigned)f2bfbits(a) | ((unsigned)f2bfbits(b) << 16);
}
static __device__ __forceinline__ f32x4 mfma16x16x32(ushort8_t a, ushort8_t b, f32x4 c) {
    return __builtin_amdgcn_mfma_f32_16x16x32_bf16(
        __builtin_bit_cast(bf16x8, a), __builtin_bit_cast(bf16x8, b), c, 0, 0, 0);
}

// ---------------------------------------------------------------- setup ----
__global__ void setup_kernel(const float* __restrict__ wq, const float* __restrict__ bq,
                             const float* __restrict__ wk,
                             const float* __restrict__ rel_h, const float* __restrict__ rel_w,
                             const float* __restrict__ wv, const float* __restrict__ bvp,
                             const float* __restrict__ gamma, const float* __restrict__ beta,
                             const float* __restrict__ mean, const float* __restrict__ var,
                             const float* __restrict__ fc1w,
                             char* __restrict__ ws)
{
    __hip_bfloat16* GA  = (__hip_bfloat16*)(ws + OFF_G);
    __hip_bfloat16* WA  = (__hip_bfloat16*)(ws + OFF_WVT);
    float*          Rm  = (float*)(ws + OFF_RT);
    float*          BnS = (float*)(ws + OFF_BNS);
    float*          Bi2 = (float*)(ws + OFF_BNB);
    __hip_bfloat16* W1  = (__hip_bfloat16*)(ws + OFF_W1);

    int idx = blockIdx.x * blockDim.x + threadIdx.x;
    if (idx < 16384) {
        int c = idx >> 7, a = idx & 127;     // GA[c][a] = sum_o wq[o,a]*wk[o,c]
        float s = 0.f;
        for (int o = 0; o < 128; ++o) s += wq[o * 128 + a] * wk[o * 128 + c];
        GA[idx] = __float2bfloat16(s);
    } else if (idx < 32768) {
        int t = idx - 16384;                 // WA[oc][j] = wv[oc][j] * inv[oc]
        int oc = t >> 7;
        float inv = gamma[oc] * rsqrtf(var[oc] + 1e-5f);
        WA[t] = __float2bfloat16(wv[t] * inv);
    } else if (idx < 34304) {
        int t = idx - 32768;                 // Rm[c][i]
        int c = t / 12, i = t - c * 12;
        float s = 0.f;
        for (int o = 0; o < 128; ++o)
            s += bq[o] * wk[o * 128 + c] + wq[o * 128 + c] * (rel_h[o * 12 + i] + rel_w[o]);
        Rm[t] = s;
    } else if (idx < 34432) {
        int c = idx - 34304;
        float inv = gamma[c] * rsqrtf(var[c] + 1e-5f);
        BnS[c] = inv;
        Bi2[c] = bvp[c] * inv + beta[c] - mean[c] * inv;
    } else if (idx < 300672) {
        int t = idx - 34432;                 // W1[h][k] = fc1w[h][k] (identity order)
        int h = t / 1280, k = t - h * 1280;
        W1[t] = (h < 200) ? __float2bfloat16(fc1w[h * 1280 + k])
                          : __float2bfloat16(0.f);
    } else if (idx < 300736) {
        // ---- MFMA fragment-layout probe (one full wave) ----
        int l = idx - 300672;
        int m = l & 15, g = l >> 4;
        ushort8_t av, bv8;
        for (int j = 0; j < 8; ++j) {
            int k = g * 8 + j;
            float aval = (float)(((m * 5 + k * 3) % 7) - 3);
            float bval = (float)(((k * 11 + m * 2) % 5) - 2);
            av[j]  = (unsigned short)(__float_as_uint(aval) >> 16);
            bv8[j] = (unsigned short)(__float_as_uint(bval) >> 16);
        }
        f32x4 zero = {0.f, 0.f, 0.f, 0.f};
        f32x4 d = mfma16x16x32(av, bv8, zero);
        bool ok = true;
        int col = l & 15;
        for (int r = 0; r < 4; ++r) {
            int row = g * 4 + r;
            float ref = 0.f;
            for (int k = 0; k < 32; ++k)
                ref += (float)(((row * 5 + k * 3) % 7) - 3) *
                       (float)(((k * 11 + col * 2) % 5) - 2);
            if (d[r] != ref) ok = false;
        }
        unsigned long long ball = __ballot(ok ? 1 : 0);
        if (l == 0) *(int*)(ws + OFF_FLAG) = (ball == ~0ull) ? 1 : 0;
    }
}

// ------------------------------------------------- MFMA attention stage ----
// R9 structure EXACTLY, with __launch_bounds__(256,2).
// Rationale: at (256,4) the allocator targets 64 VGPR but persistent state
// (gfrag 32 + wfrag 32 + rm 8 + bias2 2 = 74) exceeds it -> weights get
// REMATERIALIZED from global every group (16 hidden VMEM loads/wave/group on
// the serial chain). (256,2) lets the allocator keep them resident; LDS
// (34816 B) still caps residency at 4 blocks/CU, and VGPR<=128 preserves
// 4 waves/SIMD. Tripwire: VGPR_Count must land in (64,128]; FETCH unchanged.
#define XB_H   0        // Xb  [64][128] u16, chunk-XOR swizzled (X^T per batch)
#define TZY_H  8192     // u16: t' [64][128] swizzled; after bar3: Y [4][128][16]
#define PP_H   16384    // u16: P [4][16][16] (row m, col n; zero-padded)

__launch_bounds__(256, 2)
__global__ void attn_kernel(const float* __restrict__ x,
                            const char* __restrict__ ws,
                            __hip_bfloat16* __restrict__ pooled)
{
    __shared__ __align__(16) char lds[34816];
    unsigned short* LH = (unsigned short*)lds;

    const int tid = threadIdx.x;
    const int w = tid >> 6, l = tid & 63, g = l >> 4, lr = l & 15;

    const unsigned short* GA = (const unsigned short*)(ws + OFF_G);
    const unsigned short* WA = (const unsigned short*)(ws + OFF_WVT);
    const float* Rm  = (const float*)(ws + OFF_RT);
    const float* Bi2 = (const float*)(ws + OFF_BNB);

    // persistent per-wave weight fragments + per-lane bias + Rm registers
    ushort8_t gfrag[2][4], wfrag[2][4];
    float bias2v[2], rm[2][4];
    #pragma unroll
    for (int mi = 0; mi < 2; ++mi) {
        int mt = w + mi * 4;
        #pragma unroll
        for (int kt = 0; kt < 4; ++kt) {
            gfrag[mi][kt] = *(const ushort8_t*)(GA + (mt * 16 + lr) * 128 + kt * 32 + g * 8);
            wfrag[mi][kt] = *(const ushort8_t*)(WA + (mt * 16 + lr) * 128 + kt * 32 + g * 8);
        }
        bias2v[mi] = Bi2[mt * 16 + lr];
        #pragma unroll
        for (int r = 0; r < 4; ++r)
            rm[mi][r] = (lr < 12) ? Rm[(mt * 16 + g * 4 + r) * 12 + lr] : 0.f;
    }

    const ushort8_t zero8 = {0, 0, 0, 0, 0, 0, 0, 0};
    // zero the pad rows (n = bb*16 + 12..15) of Xb once — DO NOT REMOVE (R8)
    {
        int rr = tid >> 4, bb = rr >> 2, sub = rr & 3;
        int n = bb * 16 + 12 + sub;
        *(ushort8_t*)(LH + XB_H + n * 128 + (tid & 15) * 8) = zero8;
    }

    const int c = tid & 127, bh = tid >> 7;   // x-load mapping

    for (int grp = 0; grp < 4; ++grp) {
        const int b0g = blockIdx.x * 16 + grp * 4;

        // ---- load x, write Xb (swizzled X^T rows n=bl*16+i, rows 0..11 only)
        #pragma unroll
        for (int b2 = 0; b2 < 2; ++b2) {
            int bl = bh * 2 + b2;
            const float4* xp = (const float4*)(x + ((size_t)(b0g + bl) * 128 + c) * 12);
            float4 xa = xp[0], xb4 = xp[1], xc4 = xp[2];
            float xv[12] = {xa.x, xa.y, xa.z, xa.w, xb4.x, xb4.y, xb4.z, xb4.w,
                            xc4.x, xc4.y, xc4.z, xc4.w};
            #pragma unroll
            for (int i = 0; i < 12; ++i) {
                int n = bl * 16 + i;
                LH[XB_H + n * 128 + (((c >> 3) ^ i) << 3) + (c & 7)] = f2bfbits(xv[i]);
            }
        }
        __syncthreads();   // bar1: Xb ready; prev-group TZY/PP reads all done

        // ---- s1: t' = G^T X + R(reg)  -> TZ (transposed [n][c], swizzled)
        #pragma unroll
        for (int nt = 0; nt < 4; ++nt) {
            int n = nt * 16 + lr;
            ushort8_t bf[4];
            #pragma unroll
            for (int kt = 0; kt < 4; ++kt)
                bf[kt] = *(const ushort8_t*)(LH + XB_H + n * 128 + ((((kt << 2) + g) ^ lr) << 3));
            #pragma unroll
            for (int mi = 0; mi < 2; ++mi) {
                f32x4 acc = {0.f, 0.f, 0.f, 0.f};
                #pragma unroll
                for (int kt = 0; kt < 4; ++kt) acc = mfma16x16x32(gfrag[mi][kt], bf[kt], acc);
                int ocb = (w + mi * 4) * 16 + g * 4;
                float v0 = acc[0] + rm[mi][0];
                float v1 = acc[1] + rm[mi][1];
                float v2 = acc[2] + rm[mi][2];
                float v3 = acc[3] + rm[mi][3];
                unsigned off = TZY_H + n * 128 + (((ocb >> 3) ^ lr) << 3) + ((g & 1) << 2);
                *(unsigned*)(LH + off)     = pack2bf(v0, v1);
                *(unsigned*)(LH + off + 2) = pack2bf(v2, v3);
            }
        }
        __syncthreads();   // bar2: t' ready

        // ---- s2: S = t'^T X (wave's own batch), softmax rows -> PP[m][n]
        {
            int n = w * 16 + lr;
            f32x4 s = {0.f, 0.f, 0.f, 0.f};
            #pragma unroll
            for (int kt = 0; kt < 4; ++kt) {
                unsigned ch = (((kt << 2) + g) ^ lr) << 3;
                ushort8_t af = *(const ushort8_t*)(LH + TZY_H + n * 128 + ch);
                ushort8_t bf = *(const ushort8_t*)(LH + XB_H + n * 128 + ch);
                s = mfma16x16x32(af, bf, s);
            }
            bool jv = (lr < 12);
            float mx[4], ev[4], sum[4];
            #pragma unroll
            for (int r = 0; r < 4; ++r) mx[r] = jv ? s[r] : -3.0e38f;
            #pragma unroll
            for (int d = 1; d < 16; d <<= 1) {
                #pragma unroll
                for (int r = 0; r < 4; ++r) mx[r] = fmaxf(mx[r], __shfl_xor(mx[r], d));
            }
            #pragma unroll
            for (int r = 0; r < 4; ++r) { ev[r] = jv ? __expf(s[r] - mx[r]) : 0.f; sum[r] = ev[r]; }
            #pragma unroll
            for (int d = 1; d < 16; d <<= 1) {
                #pragma unroll
                for (int r = 0; r < 4; ++r) sum[r] += __shfl_xor(sum[r], d);
            }
            #pragma unroll
            for (int r = 0; r < 4; ++r)
                LH[PP_H + w * 256 + (g * 4 + r) * 16 + lr] = f2bfbits(ev[r] / sum[r]);
        }
        __syncthreads();   // bar3: t' reads done -> TZ space reusable as Y

        // ---- s2b: Y = Wv' X  -> Y[bb][oc][i] (over TZ space)
        #pragma unroll
        for (int nt = 0; nt < 4; ++nt) {
            int n = nt * 16 + lr;
            ushort8_t bf[4];
            #pragma unroll
            for (int kt = 0; kt < 4; ++kt)
                bf[kt] = *(const ushort8_t*)(LH + XB_H + n * 128 + ((((kt << 2) + g) ^ lr) << 3));
            #pragma unroll
            for (int mi = 0; mi < 2; ++mi) {
                f32x4 acc = {0.f, 0.f, 0.f, 0.f};
                #pragma unroll
                for (int kt = 0; kt < 4; ++kt) acc = mfma16x16x32(wfrag[mi][kt], bf[kt], acc);
                int ocb = (w + mi * 4) * 16 + g * 4;
                #pragma unroll
                for (int r = 0; r < 4; ++r)
                    LH[TZY_H + nt * 2048 + (ocb + r) * 16 + lr] = f2bfbits(acc[r]);
            }
        }
        __syncthreads();   // bar4: Y + PP ready

        // ---- s3: out^T = P . Y^T + bias2; ReLU+pool(3) in regs; u32 stores
        // pooled layout: [b][c*10 + m] -> 20 contiguous B per (b,oc).
        #pragma unroll
        for (int mi = 0; mi < 2; ++mi) {
            int mt = w + mi * 4;
            float bias = bias2v[mi];
            #pragma unroll
            for (int bb = 0; bb < 4; ++bb) {
                ushort8_t af = (g < 2)
                    ? *(const ushort8_t*)(LH + PP_H + bb * 256 + lr * 16 + g * 8) : zero8;
                ushort8_t bfy = (g < 2)
                    ? *(const ushort8_t*)(LH + TZY_H + bb * 2048 + (mt * 16 + lr) * 16 + g * 8)
                    : zero8;
                f32x4 o = {bias, bias, bias, bias};
                o = mfma16x16x32(af, bfy, o);
                float s0 = __shfl_down(o[0], 16);
                float s1 = __shfl_down(o[1], 16);
                float p0 = fmaxf(fmaxf(fmaxf(o[0], o[1]), o[2]), 0.f);
                float p1 = fmaxf(fmaxf(fmaxf(o[1], o[2]), o[3]), 0.f);
                float p2 = fmaxf(fmaxf(fmaxf(o[2], o[3]), s0), 0.f);
                float p3 = fmaxf(fmaxf(fmaxf(o[3], s0), s1), 0.f);
                unsigned* pw = (unsigned*)((unsigned short*)pooled
                             + (size_t)(b0g + bb) * 1280 + (mt * 16 + lr) * 10 + g * 4);
                if (g < 2) { pw[0] = pack2bf(p0, p1); pw[1] = pack2bf(p2, p3); }
                else if (g == 2) pw[0] = pack2bf(p0, p1);
            }
        }
        // no end barrier: next iter's Xb write touches only rows bl*16+0..11,
        // disjoint from everything read after bar4; bar1 orders the rest.
    }
}

// ----------------------------------------------------------- fc1+fc2 ----
__launch_bounds__(512, 1)
__global__ void fc_kernel(const __hip_bfloat16* __restrict__ pooled_bf,
                          const char* __restrict__ ws,
                          const float* __restrict__ fc1b,
                          const float* __restrict__ fc2w, const float* __restrict__ fc2b,
                          float* __restrict__ out)
{
    __shared__ char smem[54272];
    const int tid = threadIdx.x;
    const int b0  = blockIdx.x * 128;
    const unsigned short* P  = (const unsigned short*)pooled_bf;
    const unsigned short* W1 = (const unsigned short*)(ws + OFF_W1);
    unsigned short* hid = (unsigned short*)smem;
    const int flag = *(const int*)(ws + OFF_FLAG);

    if (flag) {
        const int l = tid & 63, w = tid >> 6;
        const int lrow = l & 15, g = l >> 4;
        f32x4 acc[13];
        #pragma unroll
        for (int nt = 0; nt < 13; ++nt) acc[nt] = (f32x4){0.f, 0.f, 0.f, 0.f};

        const int pr = tid >> 2, pc = tid & 3;
        const size_t pbase = (size_t)(b0 + pr) * 1280 + pc * 8;
        const int i1 = tid, i2 = tid + 512;
        const int h1 = i1 >> 2, c1 = i1 & 3;
        const int h2 = i2 >> 2, c2 = i2 & 3;
        const bool has2 = (i2 < 832);

        ushort8_t pReg, w1a, w1b;
        pReg = *(const ushort8_t*)(P + pbase);
        w1a  = *(const ushort8_t*)(W1 + (size_t)h1 * 1280 + c1 * 8);
        if (has2) w1b = *(const ushort8_t*)(W1 + (size_t)h2 * 1280 + c2 * 8);
        *(ushort8_t*)(smem + tid * 16) = pReg;
        *(ushort8_t*)(smem + 8192 + i1 * 16) = w1a;
        if (has2) *(ushort8_t*)(smem + 8192 + i2 * 16) = w1b;
        __syncthreads();

        int cur = 0;
        for (int ks = 0; ks < 40; ++ks) {
            if (ks + 1 < 40) {
                pReg = *(const ushort8_t*)(P + pbase + (size_t)(ks + 1) * 32);
                w1a  = *(const ushort8_t*)(W1 + (size_t)h1 * 1280 + (ks + 1) * 32 + c1 * 8);
                if (has2) w1b = *(const ushort8_t*)(W1 + (size_t)h2 * 1280 + (ks + 1) * 32 + c2 * 8);
            }
            const unsigned short* Pt = (const unsigned short*)(smem + (cur ? 21504 : 0));
            const unsigned short* Wt = (const unsigned short*)(smem + (cur ? 29696 : 8192));
            ushort8_t A = *(const ushort8_t*)(Pt + (w * 16 + lrow) * 32 + g * 8);
            #pragma unroll
            for (int nt = 0; nt < 13; ++nt) {
                ushort8_t Bf = *(const ushort8_t*)(Wt + (nt * 16 + lrow) * 32 + g * 8);
                acc[nt] = mfma16x16x32(A, Bf, acc[nt]);
            }
            __syncthreads();
            if (ks + 1 < 40) {
                char* dp = smem + ((cur ^ 1) ? 21504 : 0);
                char* dw = smem + ((cur ^ 1) ? 29696 : 8192);
                *(ushort8_t*)(dp + tid * 16) = pReg;
                *(ushort8_t*)(dw + i1 * 16) = w1a;
                if (has2) *(ushort8_t*)(dw + i2 * 16) = w1b;
            }
            __syncthreads();
            cur ^= 1;
        }
        #pragma unroll
        for (int nt = 0; nt < 13; ++nt) {
            int h = nt * 16 + lrow;
            float bias = (h < 200) ? fc1b[h] : 0.f;
            #pragma unroll
            for (int r = 0; r < 4; ++r) {
                float v = fmaxf(acc[nt][r] + bias, 0.f);
                int row = w * 16 + g * 4 + r;
                hid[row * 210 + h] = f2bfbits(v);
            }
        }
    } else {
        for (int i = tid; i < 128 * 200; i += 512) {
            int bb = i / 200, h = i - bb * 200;
            float s = fc1b[h];
            const unsigned short* prow = P + (size_t)(b0 + bb) * 1280;
            const unsigned short* wrow = W1 + (size_t)h * 1280;
            for (int j = 0; j < 1280; ++j)
                s += bfbits2f(prow[j]) * bfbits2f(wrow[j]);
            hid[bb * 210 + h] = f2bfbits(fmaxf(s, 0.f));
        }
    }
    __syncthreads();

    if (tid < 256) {
        int bb = tid >> 1, o = tid & 1;
        float s = fc2b[o];
        const unsigned short* hp = hid + bb * 210;
        const float* wp = fc2w + o * 200;
        #pragma unroll 8
        for (int j = 0; j < 200; ++j)
            s += bfbits2f(hp[j]) * wp[j];
        out[(size_t)(b0 + bb) * 2 + o] = 1.f / (1.f + __expf(-s));
    }
}

// ------------------------------------------------------------- launch ----
extern "C" void kernel_launch(void* const* d_in, const int* in_sizes, int n_in,
                              void* d_out, int out_size, void* d_ws, size_t ws_size,
                              hipStream_t stream)
{
    const float* x     = (const float*)d_in[0];
    const float* wq    = (const float*)d_in[1];
    const float* bq    = (const float*)d_in[2];
    const float* wk    = (const float*)d_in[3];
    // d_in[4] = bk: cancels under softmax row-invariance — unused.
    const float* wv    = (const float*)d_in[5];
    const float* bv    = (const float*)d_in[6];
    const float* rel_h = (const float*)d_in[7];
    const float* rel_w = (const float*)d_in[8];
    const float* gamma = (const float*)d_in[9];
    const float* beta  = (const float*)d_in[10];
    const float* mean  = (const float*)d_in[11];
    const float* var   = (const float*)d_in[12];
    const float* fc1w  = (const float*)d_in[13];
    const float* fc1b  = (const float*)d_in[14];
    const float* fc2w  = (const float*)d_in[15];
    const float* fc2b  = (const float*)d_in[16];

    char* ws = (char*)d_ws;
    __hip_bfloat16* pooled = (__hip_bfloat16*)(ws + OFF_P);
    float* out = (float*)d_out;

    setup_kernel<<<1175, 256, 0, stream>>>(wq, bq, wk, rel_h, rel_w, wv, bv,
                                           gamma, beta, mean, var, fc1w, ws);
    attn_kernel<<<2048, 256, 0, stream>>>(x, ws, pooled);
    fc_kernel<<<256, 512, 0, stream>>>(pooled, ws, fc1b, fc2w, fc2b, out);
}